// Round 20
// baseline (286.461 us; speedup 1.0000x reference)
//
#include <hip/hip_runtime.h>
#include <math.h>

// B=32, Cin=64, H=W=56, Cout=128, K=3 pad=1 -> D=576, out (32,128,56,56) fp32
#define B_    32
#define CIN   64
#define HH    56
#define WW    56
#define COUT  128
#define DD    576
#define KC    384            // OpenBLAS kc split (verified R9)
#define LPX   (HH*WW)        // 3136
#define TOTAL (B_*COUT*LPX)
#define NX    (B_*CIN*LPX)   // 6422528
#define MARGIN 4e-4f         // worst-case split-bf16 + reorder bound (validated R15-19)

typedef __attribute__((ext_vector_type(8)))  short  short8;
typedef __attribute__((ext_vector_type(16))) float  float16v;

__device__ __forceinline__ unsigned short bf16_rne(float f) {
    unsigned u = __float_as_uint(f);
    unsigned r = u + 0x7FFFu + ((u >> 16) & 1u);
    return (unsigned short)(r >> 16);
}
__device__ __forceinline__ float bf16_to_f(unsigned short h) {
    return __uint_as_float(((unsigned)h) << 16);
}

// ---- bit-exact numpy FLOAT_sin (npyv FMA path) — verified R9 ----
__device__ __forceinline__ float np_sinf(float x) {
#pragma clang fp contract(off)
    const float rint_cvt = 0x1.8p+23f;
    float q = __fmul_rn(x, 0x1.45f306p-1f);
    q = __fadd_rn(q, rint_cvt);
    q = __fsub_rn(q, rint_cvt);
    float r = fmaf(q, -0x1.921fb0p+0f, x);
    r = fmaf(q, -0x1.5110b4p-22f, r);
    r = fmaf(q, -0x1.846988p-48f, r);
    float r2 = __fmul_rn(r, r);
    float s = fmaf(0x1.7d3bbcp-19f, r2, -0x1.a06bbap-13f);
    s = fmaf(s, r2, 0x1.11119ap-7f);
    s = fmaf(s, r2, -0x1.555556p-3f);
    s = __fmul_rn(s, r2);
    s = fmaf(s, r, r);
    float c = fmaf(0x1.98e616p-16f, r2, -0x1.6c06dcp-10f);
    c = fmaf(c, r2, 0x1.55553cp-5f);
    c = fmaf(c, r2, -0.5f);
    c = fmaf(c, r2, 1.0f);
    int iq = (int)q;
    float res = (iq & 1) ? c : s;
    unsigned sgn = ((unsigned)(iq & 2)) << 30;
    return __uint_as_float(__float_as_uint(res) ^ sgn);
}
__device__ __forceinline__ int dec_np(float z) {
    float s = np_sinf(z);
    return (__fmul_rn(s, s) > 0.5f) ? 1 : 0;
}

// ---- prep: W pre-tiled into per-chunk FRAG order; x pre-split (vectorized) ----
// Whp/Wlp layout: [chunk18][t4][s2][half2][lm32][j8] shorts; element =
// W[o=t*32+lm][d=ck*32+s*16+half*8+j] split hi/lo. K-loop staging becomes a
// perfectly-coalesced linear copy (the R15-19 scattered W loads are gone).
__global__ __launch_bounds__(256)
void prep_w2(const float* __restrict__ W, unsigned short* __restrict__ Whp,
             unsigned short* __restrict__ Wlp, unsigned* __restrict__ wcount) {
    int i = blockIdx.x * 256 + threadIdx.x;
    if (i == 0) *wcount = 0;
    if (i >= 18 * 4096) return;
    int ck  = i >> 12;
    int r12 = i & 4095;
    int t    = r12 >> 10;
    int s    = (r12 >> 9) & 1;
    int half = (r12 >> 8) & 1;
    int lm   = (r12 >> 3) & 31;
    int j    = r12 & 7;
    int o = t * 32 + lm;
    int d = ck * 32 + s * 16 + half * 8 + j;
    float w = W[(size_t)o * DD + d];
    unsigned short h = bf16_rne(w);
    Whp[i] = h;
    Wlp[i] = bf16_rne(w - bf16_to_f(h));
}
__global__ __launch_bounds__(256)
void prep_x(const float* __restrict__ x, unsigned* __restrict__ xs) {
    int i4 = blockIdx.x * 256 + threadIdx.x;
    if (i4 * 4 >= NX) return;
    float4 f = *(const float4*)(x + (size_t)i4 * 4);
    unsigned o[4];
    float ff[4] = {f.x, f.y, f.z, f.w};
#pragma unroll
    for (int e = 0; e < 4; ++e) {
        unsigned short h = bf16_rne(ff[e]);
        unsigned short l = bf16_rne(ff[e] - bf16_to_f(h));
        o[e] = (unsigned)h | ((unsigned)l << 16);
    }
    *(uint4*)(xs + (size_t)i4 * 4) = make_uint4(o[0], o[1], o[2], o[3]);
}

// ---- MFMA conv: block = 128 o x 8x8 spatial px; grid (7,7,32) ----
// Full 64-channel halo staged ONCE (coalesced); K-loop has ZERO scattered
// global access: W = linear coalesced copy, P built from LDS sX.
#define FRAG(t, s, hf, ln)  (((t) * 1024) + ((s) * 512) + ((hf) * 256) + ((ln) * 8))
#define XSTR 12
#define XCH  (10 * XSTR)     // 120 u32 per channel
__global__ __launch_bounds__(256, 2)
void conv_mfma(const unsigned* __restrict__ xs,
               const unsigned short* __restrict__ Whp,
               const unsigned short* __restrict__ Wlp,
               const float* __restrict__ bias,
               float* __restrict__ out,
               unsigned* __restrict__ wcount,
               unsigned* __restrict__ wlist,
               unsigned wcap) {
    __shared__ __align__(16) unsigned short sWh[4096];   // 8 KB
    __shared__ __align__(16) unsigned short sWl[4096];   // 8 KB
    __shared__ __align__(16) unsigned short sPh[2048];   // 4 KB
    __shared__ __align__(16) unsigned short sPl[2048];   // 4 KB
    __shared__ __align__(16) unsigned sX[CIN * XCH];     // 30 KB pre-split halo

    const int tid = threadIdx.x;
    const int x0 = blockIdx.x * 8;
    const int y0 = blockIdx.y * 8;
    const int b  = blockIdx.z;

    // ---- stage full x halo once: 64 ch x 10x10 (stride 12), zeros in pad ----
    {
        const unsigned* xb = xs + (size_t)b * CIN * LPX;
        for (int t = tid; t < CIN * 100; t += 256) {
            int c   = t / 100;
            int rem = t - c * 100;
            int r   = rem / 10;
            int p   = rem - r * 10;
            int gy = y0 + r - 1, gx = x0 + p - 1;
            unsigned v = 0u;
            if ((unsigned)gy < HH && (unsigned)gx < WW)
                v = xb[c * LPX + gy * WW + gx];
            sX[c * XCH + r * XSTR + p] = v;
        }
    }

    // staging ids (P build): pair = d-pair 0..15, plane = px 0..15
    const int plane = tid & 15;
    const int pair  = tid >> 4;
    const int s_st  = pair >> 3;
    const int h_st  = (pair >> 2) & 1;
    const int j2_st = pair & 3;
    // spatial offsets of this thread's 4 px slots (px = plane + r*16)
    int spat[4];
#pragma unroll
    for (int r = 0; r < 4; ++r) {
        int px = plane + r * 16;
        spat[r] = (px >> 3) * XSTR + (px & 7);
    }

    // compute ids
    const int w    = tid >> 6;
    const int lane = tid & 63;
    const int lm   = lane & 31;
    const int half = lane >> 5;
    const int aw   = w >> 1;
    const int nw   = w & 1;

    float16v acc[2];
#pragma unroll
    for (int a = 0; a < 2; ++a)
#pragma unroll
        for (int i = 0; i < 16; ++i) acc[a][i] = 0.f;

    for (int k0 = 0; k0 < DD; k0 += 32) {
        const int ck = k0 >> 5;
        __syncthreads();
        // ---- stage W: linear coalesced copy of pre-tiled chunk ----
        {
            const uint4* sh = (const uint4*)(Whp + (size_t)ck * 4096);
            const uint4* sl = (const uint4*)(Wlp + (size_t)ck * 4096);
            uint4* dh = (uint4*)sWh;
            uint4* dl = (uint4*)sWl;
            uint4 a0 = sh[tid], a1 = sh[tid + 256];
            uint4 b0 = sl[tid], b1 = sl[tid + 256];
            dh[tid] = a0; dh[tid + 256] = a1;
            dl[tid] = b0; dl[tid + 256] = b1;
        }
        // ---- build P from sX (LDS->LDS, zero global) ----
        {
            int d0 = k0 + pair * 2;
            // c = d/9 (magic 7282>>16 valid for d<576); t=d-9c; u=(t*11)>>5; v=t-3u
            int c0 = (d0 * 7282) >> 16;  int t0 = d0 - 9 * c0;
            int u0 = (t0 * 11) >> 5;     int v0 = t0 - 3 * u0;
            int d1 = d0 + 1;
            int c1 = (d1 * 7282) >> 16;  int t1 = d1 - 9 * c1;
            int u1 = (t1 * 11) >> 5;     int v1 = t1 - 3 * u1;
            int dc0 = c0 * XCH + u0 * XSTR + v0;
            int dc1 = c1 * XCH + u1 * XSTR + v1;
#pragma unroll
            for (int r = 0; r < 4; ++r) {
                unsigned g0 = sX[dc0 + spat[r]];
                unsigned g1 = sX[dc1 + spat[r]];
                unsigned hw = (g0 & 0xFFFFu) | (g1 << 16);
                unsigned lw = (g0 >> 16) | (g1 & 0xFFFF0000u);
                int pm = plane + (r & 1) * 16;
                int word = (r >> 1) * 512 + s_st * 256 + h_st * 128 + pm * 4 + j2_st;
                ((unsigned*)sPh)[word] = hw;
                ((unsigned*)sPl)[word] = lw;
            }
        }
        __syncthreads();
#pragma unroll
        for (int s = 0; s < 2; ++s) {
            short8 Ah[2], Al[2], Bh, Bl;
#pragma unroll
            for (int a = 0; a < 2; ++a) {
                int ot = aw * 2 + a;
                Ah[a] = *(const short8*)(sWh + FRAG(ot, s, half, lm));
                Al[a] = *(const short8*)(sWl + FRAG(ot, s, half, lm));
            }
            Bh = *(const short8*)(sPh + FRAG(nw, s, half, lm));
            Bl = *(const short8*)(sPl + FRAG(nw, s, half, lm));
#pragma unroll
            for (int a = 0; a < 2; ++a)
                acc[a] = __builtin_amdgcn_mfma_f32_32x32x16_bf16(Ah[a], Bh, acc[a], 0, 0, 0);
#pragma unroll
            for (int a = 0; a < 2; ++a)
                acc[a] = __builtin_amdgcn_mfma_f32_32x32x16_bf16(Ah[a], Bl, acc[a], 0, 0, 0);
#pragma unroll
            for (int a = 0; a < 2; ++a)
                acc[a] = __builtin_amdgcn_mfma_f32_32x32x16_bf16(Al[a], Bh, acc[a], 0, 0, 0);
        }
    }

    // epilogue: bias + parity decision; borderline -> worklist
    const size_t outb = (size_t)b * COUT * LPX;
    const int pxf = nw * 32 + lm;
    const int py = y0 + (pxf >> 3);
    const int pxc = x0 + (pxf & 7);
#pragma unroll
    for (int a = 0; a < 2; ++a) {
        const int obase = aw * 64 + a * 32 + 4 * half;
#pragma unroll
        for (int reg = 0; reg < 16; ++reg) {
            int o = obase + (reg & 3) + 8 * (reg >> 2);
            float z = acc[a][reg] + bias[o];
            float q = rintf(__fmul_rn(z, 0.63661975f));
            float rr = fmaf(q, -1.5707964f, z);
            float d = fabsf(fabsf(rr) - 0.78539816f);
            size_t oidx = outb + (size_t)o * LPX + py * WW + pxc;
            out[oidx] = (float)(((int)q) & 1);
            if (d < MARGIN) {
                unsigned pos = atomicAdd(wcount, 1u);
                if (pos < wcap) wlist[pos] = (unsigned)oidx;
            }
        }
    }
}

// ---- wave-cooperative fixup (R19): bit-exact replay of verified R9 path ----
__global__ __launch_bounds__(64)
void exact_fix_wave(const float* __restrict__ x,
                    const float* __restrict__ Wt,
                    const float* __restrict__ bias,
                    float* __restrict__ out,
                    const unsigned* __restrict__ wcount,
                    const unsigned* __restrict__ wlist,
                    unsigned wcap) {
#pragma clang fp contract(off)
    __shared__ float sx[4][DD];
    __shared__ float sw[4][DD];
    const int lane = threadIdx.x;
    unsigned n = *wcount;
    if (n > wcap) n = wcap;

    for (unsigned e0 = blockIdx.x * 4; e0 < n; e0 += gridDim.x * 4) {
        unsigned idxs[4];
#pragma unroll
        for (int j = 0; j < 4; ++j) {
            unsigned e = e0 + j;
            if (e >= n) { idxs[j] = 0xFFFFFFFFu; continue; }
            unsigned idx = wlist[e];
            idxs[j] = idx;
            int px = idx % WW;
            unsigned t = idx / WW;
            int py = t % HH;  t /= HH;
            int o  = t % COUT;
            int b  = t / COUT;
            const float* xc = x  + ((size_t)(b * CIN + lane)) * LPX;
            const float* wc = Wt + (size_t)o * DD + lane * 9;
#pragma unroll
            for (int u = 0; u < 3; ++u)
#pragma unroll
                for (int v = 0; v < 3; ++v) {
                    int tp = u * 3 + v;
                    int gy = py + u - 1, gx = px + v - 1;
                    float p = ((unsigned)gy < HH && (unsigned)gx < WW)
                                  ? xc[gy * WW + gx] : 0.f;
                    sx[j][lane * 9 + tp] = p;
                    sw[j][lane * 9 + tp] = wc[tp];
                }
        }
        __syncthreads();
        if (lane < 4 && idxs[lane] != 0xFFFFFFFFu) {
            const float* px_ = sx[lane];
            const float* pw_ = sw[lane];
            float accA = 0.f, accB2 = 0.f;
            for (int d = 0; d < KC; ++d)  accA  = fmaf(px_[d], pw_[d], accA);
            for (int d = KC; d < DD; ++d) accB2 = fmaf(px_[d], pw_[d], accB2);
            unsigned idx = idxs[lane];
            int o = (idx / LPX) % COUT;
            float zG = __fadd_rn(accA, accB2);
            float z  = __fadd_rn(zG, bias[o]);
            out[idx] = (float)dec_np(z);
        }
        __syncthreads();
    }
}

// ---- fallback (verified R9 path) ----
__global__ __launch_bounds__(256)
void np_emul_conv(const float* __restrict__ x,
                  const float* __restrict__ Wt,
                  const float* __restrict__ bias,
                  float* __restrict__ out) {
#pragma clang fp contract(off)
    int idx = blockIdx.x * 256 + threadIdx.x;
    if (idx >= TOTAL) return;
    int px = idx % WW;
    int t  = idx / WW;
    int py = t % HH;  t /= HH;
    int o  = t % COUT;
    int b  = t / COUT;
    const float* wrow = Wt + (size_t)o * DD;
    const float* xb   = x + (size_t)b * CIN * LPX;
    float accA = 0.f, accB2 = 0.f;
    for (int c = 0; c < CIN; ++c) {
        const float* xc = xb + c * LPX;
        const float* wc = wrow + c * 9;
        int dbase = c * 9;
#pragma unroll
        for (int u = 0; u < 3; ++u)
#pragma unroll
            for (int v = 0; v < 3; ++v) {
                int tp = u * 3 + v;
                int gy = py + u - 1, gx = px + v - 1;
                float p = ((unsigned)gy < HH && (unsigned)gx < WW) ? xc[gy * WW + gx] : 0.f;
                if (dbase + tp < KC) accA  = fmaf(p, wc[tp], accA);
                else                 accB2 = fmaf(p, wc[tp], accB2);
            }
    }
    float z = __fadd_rn(__fadd_rn(accA, accB2), bias[o]);
    out[idx] = (float)dec_np(z);
}

extern "C" void kernel_launch(void* const* d_in, const int* in_sizes, int n_in,
                              void* d_out, int out_size, void* d_ws, size_t ws_size,
                              hipStream_t stream) {
    const float* x  = (const float*)d_in[0];
    const float* Wt = (const float*)d_in[1];
    const float* bb = (const float*)d_in[2];
    float* out = (float*)d_out;

    const size_t WSPLIT = (size_t)18 * 4096 * 2;          // 147456 B each
    const size_t XS     = (size_t)NX * 4;                 // 25.7 MB
    const size_t FIXED  = 2 * WSPLIT + XS + 4;

    if (ws_size >= FIXED + 65536) {
        unsigned short* Whp = (unsigned short*)d_ws;
        unsigned short* Wlp = Whp + 18 * 4096;
        unsigned* xsv    = (unsigned*)((char*)d_ws + 2 * WSPLIT);
        unsigned* wcount = (unsigned*)((char*)d_ws + 2 * WSPLIT + XS);
        unsigned* wlist  = wcount + 1;
        size_t avail = (ws_size - FIXED) / 4;
        unsigned wcap = (avail > 2000000u) ? 2000000u : (unsigned)avail;

        prep_w2<<<dim3((18 * 4096 + 255) / 256), dim3(256), 0, stream>>>(Wt, Whp, Wlp, wcount);
        prep_x<<<dim3((NX / 4 + 255) / 256), dim3(256), 0, stream>>>(x, xsv);
        conv_mfma<<<dim3(7, 7, B_), dim3(256), 0, stream>>>(xsv, Whp, Wlp, bb, out,
                                                            wcount, wlist, wcap);
        exact_fix_wave<<<dim3(1024), dim3(64), 0, stream>>>(x, Wt, bb, out,
                                                            wcount, wlist, wcap);
    } else {
        np_emul_conv<<<(TOTAL + 255) / 256, 256, 0, stream>>>(x, Wt, bb, out);
    }
}